// Round 16
// baseline (45.233 us; speedup 1.0000x reference)
//
#include <hip/hip_runtime.h>
#include <hip/hip_bf16.h>
#include <math.h>

#define BATCH 2
#define CIN 64
#define NSP 4096
#define CK 32
#define CV 64
#define COUT 64
#define EPS 1e-5f
// 32^(-1/4) * sqrt(log2(e)) — folded into K producer so p = exp2(s)
#define S4L 0.5050097680523077f

#define KB 64                    // keys per chunk
#define NW 8                     // waves per attn block
#define KPW (NSP / NW)           // 512 keys per wave
#define NCH (KPW / KB)           // 8 chunks per wave

typedef unsigned short ushort_t;
using bf16x8 = __attribute__((ext_vector_type(8))) short;
using bf16x4 = __attribute__((ext_vector_type(4))) short;
using f32x4  = __attribute__((ext_vector_type(4))) float;
using float4_t = __attribute__((ext_vector_type(4))) float;

__device__ inline ushort_t f2bf(float f) {
  __hip_bfloat16 h = __float2bfloat16(f);   // RNE; compiler pairs into cvt_pk
  return *reinterpret_cast<ushort_t*>(&h);
}

// ---------------------------------------------------------------------------
// Kernel 1: fused transpose + MFMA K/V projections, 512 threads = 8 waves.
// (unchanged from r15 — verified)
// ---------------------------------------------------------------------------
__global__ __launch_bounds__(512) void kv_kernel(
    const float* __restrict__ x,
    const float* __restrict__ key_w,
    const float* __restrict__ bn_gamma,
    const float* __restrict__ bn_beta,
    const float* __restrict__ bn_mean,
    const float* __restrict__ bn_var,
    const float* __restrict__ value_w,
    const float* __restrict__ value_b,
    ushort_t* __restrict__ KbT,
    ushort_t* __restrict__ Vbf) {
  __shared__ ushort_t XL[32][66];

  int tid = threadIdx.x, wid = tid >> 6, lane = tid & 63;
  int l15 = lane & 15, g = lane >> 4;
  int b  = blockIdx.x / (NSP / 32);
  int n0 = (blockIdx.x % (NSP / 32)) * 32;

  {
    int n = tid & 31, c4 = tid >> 5;          // c4: 0..15
    const float* xb = x + ((size_t)b * CIN + c4 * 4) * NSP + n0 + n;
#pragma unroll
    for (int j = 0; j < 4; ++j)
      XL[n][c4 * 4 + j] = f2bf(xb[(size_t)j * NSP]);
  }
  __syncthreads();

  if (wid < 4) {
    // ---- K unit: nsub = wid>>1, osub = wid&1 ----
    int nsub = wid >> 1, osub = wid & 1;
    bf16x8 a[2];
#pragma unroll
    for (int kk = 0; kk < 2; ++kk)
      a[kk] = *(const bf16x8*)&XL[nsub * 16 + l15][kk * 32 + g * 8];
    bf16x8 bb[2];
#pragma unroll
    for (int kk = 0; kk < 2; ++kk) {
      const float* wp = key_w + (osub * 16 + l15) * CIN + kk * 32 + g * 8;
#pragma unroll
      for (int j = 0; j < 8; ++j) bb[kk][j] = (short)f2bf(wp[j]);
    }
    f32x4 d = {0.f, 0.f, 0.f, 0.f};
    d = __builtin_amdgcn_mfma_f32_16x16x32_bf16(a[0], bb[0], d, 0, 0, 0);
    d = __builtin_amdgcn_mfma_f32_16x16x32_bf16(a[1], bb[1], d, 0, 0, 0);
    int o = osub * 16 + l15;
    float sc  = bn_gamma[o] * rsqrtf(bn_var[o] + EPS);
    float scl = sc * S4L;
    float bi  = (bn_beta[o] - bn_mean[o] * sc) * S4L;
#pragma unroll
    for (int r = 0; r < 4; ++r) {
      int n = n0 + nsub * 16 + 4 * g + r;
      KbT[((size_t)b * NSP + n) * CK + o] = f2bf(d[r] * scl + bi);
    }
  } else {
    // ---- V unit: osub = wid-4 (16 o-rows), both nsub ----
    int osub = wid - 4;
    bf16x8 bbv[2][2];
#pragma unroll
    for (int nsub = 0; nsub < 2; ++nsub)
#pragma unroll
      for (int kk = 0; kk < 2; ++kk)
        bbv[nsub][kk] = *(const bf16x8*)&XL[nsub * 16 + l15][kk * 32 + g * 8];
    bf16x8 av[2];
#pragma unroll
    for (int kk = 0; kk < 2; ++kk) {
      const float* wp = value_w + (osub * 16 + l15) * CIN + kk * 32 + g * 8;
#pragma unroll
      for (int j = 0; j < 8; ++j) av[kk][j] = (short)f2bf(wp[j]);
    }
#pragma unroll
    for (int nsub = 0; nsub < 2; ++nsub) {
      f32x4 d = {0.f, 0.f, 0.f, 0.f};
      d = __builtin_amdgcn_mfma_f32_16x16x32_bf16(av[0], bbv[nsub][0], d, 0, 0, 0);
      d = __builtin_amdgcn_mfma_f32_16x16x32_bf16(av[1], bbv[nsub][1], d, 0, 0, 0);
#pragma unroll
      for (int r = 0; r < 4; ++r) {
        int o = osub * 16 + 4 * g + r;
        int n = n0 + nsub * 16 + l15;
        Vbf[((size_t)b * CV + o) * NSP + n] = f2bf(d[r] + value_b[o]);
      }
    }
  }
}

// ---------------------------------------------------------------------------
// Kernel 2: FUSED attention + projection. V is REGISTER-staged (no V LDS):
// the 16 8-B fragment spans of plain [cv][n] V load directly into
// double-buffered bf16x4 registers, issued after PV so the compiler's
// automatic vmcnt wait on V(t) transitively proves K(t+1) landed (FIFO) —
// zero manual vmcnt in the loop. K keeps LDS dbuf (2x4KB/wave). 80 KB LDS.
// 8 waves (2/SIMD), barrier-free main loop. grid = B*(N/32).
// ---------------------------------------------------------------------------
__global__ __launch_bounds__(512) void attn_proj_kernel(
    const ushort_t* __restrict__ KbT,
    const ushort_t* __restrict__ Vbf,
    const float* __restrict__ Ww,
    const float* __restrict__ Wb,
    const float* __restrict__ gamma,
    const float* __restrict__ x,
    float* __restrict__ out) {
  // per-wave 4096 ush (8 KB): K buf0 [0,2048), K buf1 [2048,4096)
  __shared__ __align__(16) ushort_t SMEM[NW * 4096];   // 64 KB
  __shared__ __align__(16) float WL[COUT * CV];        // 16 KB

  int tid = threadIdx.x, wid = tid >> 6, lane = tid & 63;
  int l15 = lane & 15, g = lane >> 4;
  int b  = blockIdx.x / (NSP / 32);
  int q0 = (blockIdx.x % (NSP / 32)) * 32;

  const ushort_t* Kb = KbT + (size_t)b * NSP * CK;
  const ushort_t* Vb = Vbf + (size_t)b * CV * NSP;

  // ---- stage W into LDS (16 KB, linear; consumed broadcast in epilogue) ----
#pragma unroll
  for (int i = 0; i < 2; ++i) {
    size_t boff = (size_t)i * 8192 + wid * 1024;       // wave-uniform byte base
    const float* src = (const float*)((const char*)Ww + boff + lane * 16);
    float* dst = (float*)((char*)WL + boff);
    __builtin_amdgcn_global_load_lds(
        (const __attribute__((address_space(1))) unsigned int*)src,
        (__attribute__((address_space(3))) unsigned int*)dst, 16, 0, 0);
  }

  // ---- Q fragments: all waves share the same 32 q-rows ----
  bf16x8 qf[2];
#pragma unroll
  for (int qg = 0; qg < 2; ++qg)
    qf[qg] = *(const bf16x8*)&Kb[(size_t)(q0 + qg * 16 + l15) * CK + g * 8];
  asm volatile("s_waitcnt vmcnt(0)" ::: "memory");   // clean vmcnt baseline
  __builtin_amdgcn_sched_barrier(0);

  f32x4 acc[2][4];
  float Ssum[2] = {0.f, 0.f};
#pragma unroll
  for (int qg = 0; qg < 2; ++qg)
#pragma unroll
    for (int cg = 0; cg < 4; ++cg)
#pragma unroll
      for (int r = 0; r < 4; ++r) acc[qg][cg][r] = 0.f;

  int kbase = wid * KPW;

  auto stageK = [&](int buf, int n0k) {      // 4 gload_lds of 16B
    ushort_t* dstb = &SMEM[wid * 4096 + buf * 2048];
#pragma unroll
    for (int i = 0; i < 4; ++i) {
      int off = i * 1024 + lane * 16;
      int key = off >> 6;
      int c16 = (off >> 4) & 3;
      int sw  = c16 ^ ((key >> 1) & 3);
      const ushort_t* src = Kb + (size_t)(n0k + key) * CK + sw * 8;
      __builtin_amdgcn_global_load_lds(
          (const __attribute__((address_space(1))) unsigned int*)src,
          (__attribute__((address_space(3))) unsigned int*)&dstb[i * 512], 16, 0, 0);
    }
  };

  // V register buffers: [parity][ks][cg]; statically indexed (full unroll)
  bf16x4 vlo[2][2][4], vhi[2][2][4];
  auto loadV = [&](int pb, int n0k) {        // 16 plain 8-B loads
#pragma unroll
    for (int ks = 0; ks < 2; ++ks)
#pragma unroll
      for (int cg = 0; cg < 4; ++cg) {
        const ushort_t* vr = Vb + (size_t)(cg * 16 + l15) * NSP + n0k + ks * 32 + 4 * g;
        vlo[pb][ks][cg] = *(const bf16x4*)vr;
        vhi[pb][ks][cg] = *(const bf16x4*)(vr + 16);
      }
  };

  // prologue. FIFO: K0(4), K1(4), V0(16) -> K0 done <=> vmcnt<=20
  stageK(0, kbase);
  stageK(1, kbase + KB);
  loadV(0, kbase);
  asm volatile("s_waitcnt vmcnt(20)" ::: "memory");  // K0 landed
  __builtin_amdgcn_sched_barrier(0);

#pragma unroll
  for (int t = 0; t < NCH; ++t) {
    const int cur = t & 1;
    const ushort_t* KTc = &SMEM[wid * 4096 + cur * 2048];

    // ---- QK^T (swapped): kf read once, reused for both q-groups ----
    // K(t) landed: t==0 by prologue wait; t>0 by PV(t-1)'s wait on V(t-1)
    // (V(t-1) issued after K(t) -> FIFO implies K(t) complete).
    bf16x8 kf[4];
#pragma unroll
    for (int kg = 0; kg < 4; ++kg) {
      int key = kg * 16 + l15;
      int sw  = g ^ ((key >> 1) & 3);
      kf[kg] = *(const bf16x8*)&KTc[key * CK + sw * 8];
    }
    f32x4 s[2][4];
    __builtin_amdgcn_s_setprio(1);
#pragma unroll
    for (int qg = 0; qg < 2; ++qg)
#pragma unroll
      for (int kg = 0; kg < 4; ++kg) {
        f32x4 z = {0.f, 0.f, 0.f, 0.f};
        s[qg][kg] = __builtin_amdgcn_mfma_f32_16x16x32_bf16(kf[kg], qf[qg], z, 0, 0, 0);
      }
    __builtin_amdgcn_s_setprio(0);

    // ---- p = exp2(s) + pa pack ----
    float p[2][4][4];
#pragma unroll
    for (int qg = 0; qg < 2; ++qg)
#pragma unroll
      for (int kg = 0; kg < 4; ++kg) {
        float ps = 0.f;
#pragma unroll
        for (int r = 0; r < 4; ++r) {
          p[qg][kg][r] = exp2f(s[qg][kg][r]);
          ps += p[qg][kg][r];
        }
        Ssum[qg] += ps;
      }
    bf16x8 pa[2][2];
#pragma unroll
    for (int ks = 0; ks < 2; ++ks)
#pragma unroll
      for (int qg = 0; qg < 2; ++qg)
#pragma unroll
        for (int j = 0; j < 4; ++j) {
          pa[ks][qg][j]     = (short)f2bf(p[qg][2 * ks][j]);
          pa[ks][qg][4 + j] = (short)f2bf(p[qg][2 * ks + 1][j]);
        }

    // ---- PV from V registers (compiler inserts the vmcnt wait) ----
    __builtin_amdgcn_s_setprio(1);
#pragma unroll
    for (int ks = 0; ks < 2; ++ks) {
#pragma unroll
      for (int cg = 0; cg < 4; ++cg) {
        bf16x8 vf;
#pragma unroll
        for (int j = 0; j < 4; ++j) {
          vf[j]     = vlo[cur][ks][cg][j];
          vf[4 + j] = vhi[cur][ks][cg][j];
        }
#pragma unroll
        for (int qg = 0; qg < 2; ++qg)
          acc[qg][cg] = __builtin_amdgcn_mfma_f32_16x16x32_bf16(pa[ks][qg], vf, acc[qg][cg], 0, 0, 0);
      }
    }
    __builtin_amdgcn_s_setprio(0);

    // ---- kf reads consumed; safe to overwrite K buf[cur] ----
    asm volatile("s_waitcnt lgkmcnt(0)" ::: "memory");
    __builtin_amdgcn_sched_barrier(0);

    if (t + 2 < NCH) stageK(cur, kbase + (t + 2) * KB);     // 4 gload_lds
    if (t + 1 < NCH) loadV(cur ^ 1, kbase + (t + 1) * KB);  // 16 reg loads
  }

  // ---- per-wave denom finish ----
#pragma unroll
  for (int qg = 0; qg < 2; ++qg) {
    Ssum[qg] += __shfl_xor(Ssum[qg], 16, 64);
    Ssum[qg] += __shfl_xor(Ssum[qg], 32, 64);
  }

  // ---- two-stage cross-wave reduce (64 KB scratch: 4 wave-bufs max) ----
  __syncthreads();                            // drains all LDS/VMEM; SMEM reusable
  float* red = (float*)&SMEM[0];              // [4][32 q][68]
  float* SsR = red + 4 * 32 * 68;             // [4][32]

  if (wid >= 4) {
    int w = wid - 4;
#pragma unroll
    for (int qg = 0; qg < 2; ++qg) {
#pragma unroll
      for (int cg = 0; cg < 4; ++cg)
#pragma unroll
        for (int r = 0; r < 4; ++r) {
          int ql = qg * 16 + 4 * g + r;
          red[(w * 32 + ql) * 68 + cg * 16 + l15] = acc[qg][cg][r];
        }
      if (g == 0) SsR[w * 32 + qg * 16 + l15] = Ssum[qg];
    }
  }
  __syncthreads();
  if (wid < 4) {
#pragma unroll
    for (int qg = 0; qg < 2; ++qg) {
#pragma unroll
      for (int cg = 0; cg < 4; ++cg)
#pragma unroll
        for (int r = 0; r < 4; ++r) {
          int ql = qg * 16 + 4 * g + r;
          acc[qg][cg][r] += red[(wid * 32 + ql) * 68 + cg * 16 + l15];
        }
      Ssum[qg] += SsR[wid * 32 + qg * 16 + l15];
    }
  }
  __syncthreads();
  if (wid < 4) {
#pragma unroll
    for (int qg = 0; qg < 2; ++qg) {
#pragma unroll
      for (int cg = 0; cg < 4; ++cg)
#pragma unroll
        for (int r = 0; r < 4; ++r) {
          int ql = qg * 16 + 4 * g + r;
          red[(wid * 32 + ql) * 68 + cg * 16 + l15] = acc[qg][cg][r];
        }
      if (g == 0) SsR[wid * 32 + qg * 16 + l15] = Ssum[qg];
    }
  }
  __syncthreads();

  // ---- thread-per-slot merge of 4 wave-bufs (race-free) ----
  int n  = tid & 31;
  int sl = tid >> 5;                          // 0..15 = v4 slot
  {
    float4_t m4 = *(const float4_t*)&red[n * 68 + sl * 4];
#pragma unroll
    for (int w = 1; w < 4; ++w) {
      float4_t t4 = *(const float4_t*)&red[(w * 32 + n) * 68 + sl * 4];
      m4[0] += t4[0]; m4[1] += t4[1]; m4[2] += t4[2]; m4[3] += t4[3];
    }
    *(float4_t*)&red[n * 68 + sl * 4] = m4;
  }
  if (tid < 32) {
    float ds = 0.f;
#pragma unroll
    for (int w = 0; w < 4; ++w) ds += SsR[w * 32 + tid];
    SsR[tid] = ds;
  }
  __syncthreads();

  // ---- fused proj: 512 threads, 4 outputs each; W from LDS ----
  int og = tid >> 5;                          // 0..15
  float invn = 1.f / SsR[n];

  float pacc[4];
#pragma unroll
  for (int j = 0; j < 4; ++j) pacc[j] = 0.f;
#pragma unroll
  for (int v4 = 0; v4 < 16; ++v4) {
    float4_t c4 = *(const float4_t*)&red[n * 68 + v4 * 4];
#pragma unroll
    for (int j = 0; j < 4; ++j) {
      float4_t w4 = *(const float4_t*)&WL[(og * 4 + j) * CV + v4 * 4];  // broadcast
      pacc[j] += w4[0] * c4[0] + w4[1] * c4[1] + w4[2] * c4[2] + w4[3] * c4[3];
    }
  }

  float gma = gamma[0];
#pragma unroll
  for (int j = 0; j < 4; ++j) {
    int o = og * 4 + j;
    size_t oi = ((size_t)b * COUT + o) * NSP + q0 + n;
    out[oi] = gma * (pacc[j] * invn + Wb[o]) + x[oi];
  }
}

// ---------------------------------------------------------------------------
extern "C" void kernel_launch(void* const* d_in, const int* in_sizes, int n_in,
                              void* d_out, int out_size, void* d_ws, size_t ws_size,
                              hipStream_t stream) {
  const float* x        = (const float*)d_in[0];
  const float* key_w    = (const float*)d_in[1];
  const float* bn_gamma = (const float*)d_in[2];
  const float* bn_beta  = (const float*)d_in[3];
  const float* bn_mean  = (const float*)d_in[4];
  const float* bn_var   = (const float*)d_in[5];
  const float* value_w  = (const float*)d_in[6];
  const float* value_b  = (const float*)d_in[7];
  const float* W_w      = (const float*)d_in[8];
  const float* W_b      = (const float*)d_in[9];
  const float* gamma    = (const float*)d_in[10];
  float* out = (float*)d_out;

  ushort_t* KbT = (ushort_t*)d_ws;                       // [B][N][CK]  bf16
  ushort_t* Vbf = KbT + (size_t)BATCH * NSP * CK;        // [B][CV][N]  bf16

  kv_kernel<<<BATCH * (NSP / 32), 512, 0, stream>>>(
      x, key_w, bn_gamma, bn_beta, bn_mean, bn_var, value_w, value_b, KbT, Vbf);
  attn_proj_kernel<<<BATCH * (NSP / 32), 512, 0, stream>>>(
      KbT, Vbf, W_w, W_b, gamma, x, out);
}

// Round 17
// 28.308 us; speedup vs baseline: 1.5979x; 1.5979x over previous
//
#include <hip/hip_runtime.h>
#include <hip/hip_bf16.h>
#include <math.h>

#define BATCH 2
#define CIN 64
#define NSP 4096
#define CK 32
#define CV 64
#define COUT 64
#define EPS 1e-5f
// 32^(-1/4) * sqrt(log2(e)) — folded into K producer so p = exp2(s)
#define S4L 0.5050097680523077f

#define KB 64                    // keys per chunk
#define NW 8                     // waves per attn block
#define KPW (NSP / NW)           // 512 keys per wave
#define NCH (KPW / KB)           // 8 chunks per wave

typedef unsigned short ushort_t;
using bf16x8 = __attribute__((ext_vector_type(8))) short;
using bf16x4 = __attribute__((ext_vector_type(4))) short;
using f32x4  = __attribute__((ext_vector_type(4))) float;
using float4_t = __attribute__((ext_vector_type(4))) float;

__device__ inline ushort_t f2bf(float f) {
  __hip_bfloat16 h = __float2bfloat16(f);   // RNE; compiler pairs into cvt_pk
  return *reinterpret_cast<ushort_t*>(&h);
}

// ---------------------------------------------------------------------------
// Kernel 1: fused transpose + MFMA K/V projections, 512 threads = 8 waves
// (2 waves/SIMD). One MFMA work-unit per wave: w0-3 = K (nsub x osub),
// w4-7 = V (osub). grid = B*(N/32).
// ---------------------------------------------------------------------------
__global__ __launch_bounds__(512) void kv_kernel(
    const float* __restrict__ x,
    const float* __restrict__ key_w,
    const float* __restrict__ bn_gamma,
    const float* __restrict__ bn_beta,
    const float* __restrict__ bn_mean,
    const float* __restrict__ bn_var,
    const float* __restrict__ value_w,
    const float* __restrict__ value_b,
    ushort_t* __restrict__ KbT,
    ushort_t* __restrict__ Vbf) {
  __shared__ ushort_t XL[32][66];

  int tid = threadIdx.x, wid = tid >> 6, lane = tid & 63;
  int l15 = lane & 15, g = lane >> 4;
  int b  = blockIdx.x / (NSP / 32);
  int n0 = (blockIdx.x % (NSP / 32)) * 32;

  {
    int n = tid & 31, c4 = tid >> 5;          // c4: 0..15
    const float* xb = x + ((size_t)b * CIN + c4 * 4) * NSP + n0 + n;
#pragma unroll
    for (int j = 0; j < 4; ++j)
      XL[n][c4 * 4 + j] = f2bf(xb[(size_t)j * NSP]);
  }
  __syncthreads();

  if (wid < 4) {
    // ---- K unit: nsub = wid>>1, osub = wid&1 ----
    int nsub = wid >> 1, osub = wid & 1;
    bf16x8 a[2];
#pragma unroll
    for (int kk = 0; kk < 2; ++kk)
      a[kk] = *(const bf16x8*)&XL[nsub * 16 + l15][kk * 32 + g * 8];
    bf16x8 bb[2];
#pragma unroll
    for (int kk = 0; kk < 2; ++kk) {
      const float* wp = key_w + (osub * 16 + l15) * CIN + kk * 32 + g * 8;
#pragma unroll
      for (int j = 0; j < 8; ++j) bb[kk][j] = (short)f2bf(wp[j]);
    }
    f32x4 d = {0.f, 0.f, 0.f, 0.f};
    d = __builtin_amdgcn_mfma_f32_16x16x32_bf16(a[0], bb[0], d, 0, 0, 0);
    d = __builtin_amdgcn_mfma_f32_16x16x32_bf16(a[1], bb[1], d, 0, 0, 0);
    int o = osub * 16 + l15;
    float sc  = bn_gamma[o] * rsqrtf(bn_var[o] + EPS);
    float scl = sc * S4L;
    float bi  = (bn_beta[o] - bn_mean[o] * sc) * S4L;
#pragma unroll
    for (int r = 0; r < 4; ++r) {
      int n = n0 + nsub * 16 + 4 * g + r;
      KbT[((size_t)b * NSP + n) * CK + o] = f2bf(d[r] * scl + bi);
    }
  } else {
    // ---- V unit: osub = wid-4 (16 o-rows), both nsub ----
    int osub = wid - 4;
    bf16x8 bbv[2][2];
#pragma unroll
    for (int nsub = 0; nsub < 2; ++nsub)
#pragma unroll
      for (int kk = 0; kk < 2; ++kk)
        bbv[nsub][kk] = *(const bf16x8*)&XL[nsub * 16 + l15][kk * 32 + g * 8];
    bf16x8 av[2];
#pragma unroll
    for (int kk = 0; kk < 2; ++kk) {
      const float* wp = value_w + (osub * 16 + l15) * CIN + kk * 32 + g * 8;
#pragma unroll
      for (int j = 0; j < 8; ++j) av[kk][j] = (short)f2bf(wp[j]);
    }
#pragma unroll
    for (int nsub = 0; nsub < 2; ++nsub) {
      f32x4 d = {0.f, 0.f, 0.f, 0.f};
      d = __builtin_amdgcn_mfma_f32_16x16x32_bf16(av[0], bbv[nsub][0], d, 0, 0, 0);
      d = __builtin_amdgcn_mfma_f32_16x16x32_bf16(av[1], bbv[nsub][1], d, 0, 0, 0);
#pragma unroll
      for (int r = 0; r < 4; ++r) {
        int o = osub * 16 + 4 * g + r;
        int n = n0 + nsub * 16 + l15;
        Vbf[((size_t)b * CV + o) * NSP + n] = f2bf(d[r] + value_b[o]);
      }
    }
  }
}

// ---------------------------------------------------------------------------
// Kernel 2: FUSED attention + projection (r15 exact).
// 1 block = 32 q-rows, 8 waves (2 waves/SIMD). Each wave owns keys
// [wid*512, +512): private K dbuf (2x4KB) + V single-buf (8KB), barrier-free
// main loop, per-wave counted vmcnt. 144 KB LDS. grid = B*(N/32).
// ---------------------------------------------------------------------------
__global__ __launch_bounds__(512) void attn_proj_kernel(
    const ushort_t* __restrict__ KbT,
    const ushort_t* __restrict__ Vbf,
    const float* __restrict__ Ww,
    const float* __restrict__ Wb,
    const float* __restrict__ gamma,
    const float* __restrict__ x,
    float* __restrict__ out) {
  // per-wave 8192 ush (16 KB): K buf0 [0,2048), K buf1 [2048,4096), V [4096,8192)
  __shared__ __align__(16) ushort_t SMEM[NW * 8192];   // 128 KB
  __shared__ __align__(16) float WL[COUT * CV];        // 16 KB

  int tid = threadIdx.x, wid = tid >> 6, lane = tid & 63;
  int l15 = lane & 15, g = lane >> 4;
  int b  = blockIdx.x / (NSP / 32);
  int q0 = (blockIdx.x % (NSP / 32)) * 32;

  const ushort_t* Kb = KbT + (size_t)b * NSP * CK;
  const ushort_t* Vb = Vbf + (size_t)b * CV * NSP;

  // ---- stage W into LDS (16 KB, linear; consumed broadcast in epilogue) ----
#pragma unroll
  for (int i = 0; i < 2; ++i) {
    size_t boff = (size_t)i * 8192 + wid * 1024;       // wave-uniform byte base
    const float* src = (const float*)((const char*)Ww + boff + lane * 16);
    float* dst = (float*)((char*)WL + boff);
    __builtin_amdgcn_global_load_lds(
        (const __attribute__((address_space(1))) unsigned int*)src,
        (__attribute__((address_space(3))) unsigned int*)dst, 16, 0, 0);
  }

  // ---- Q fragments: all waves share the same 32 q-rows ----
  bf16x8 qf[2];
#pragma unroll
  for (int qg = 0; qg < 2; ++qg)
    qf[qg] = *(const bf16x8*)&Kb[(size_t)(q0 + qg * 16 + l15) * CK + g * 8];
  asm volatile("s_waitcnt vmcnt(0)" ::: "memory");   // clean vmcnt baseline
  __builtin_amdgcn_sched_barrier(0);

  f32x4 acc[2][4];
  float Ssum[2] = {0.f, 0.f};
#pragma unroll
  for (int qg = 0; qg < 2; ++qg)
#pragma unroll
    for (int cg = 0; cg < 4; ++cg)
#pragma unroll
      for (int r = 0; r < 4; ++r) acc[qg][cg][r] = 0.f;

  int kbase = wid * KPW;

  auto stageK = [&](int buf, int n0k) {      // 4 loads of 16B
    ushort_t* dstb = &SMEM[wid * 8192 + buf * 2048];
#pragma unroll
    for (int i = 0; i < 4; ++i) {
      int off = i * 1024 + lane * 16;
      int key = off >> 6;
      int c16 = (off >> 4) & 3;
      int sw  = c16 ^ ((key >> 1) & 3);
      const ushort_t* src = Kb + (size_t)(n0k + key) * CK + sw * 8;
      __builtin_amdgcn_global_load_lds(
          (const __attribute__((address_space(1))) unsigned int*)src,
          (__attribute__((address_space(3))) unsigned int*)&dstb[i * 512], 16, 0, 0);
    }
  };
  auto stageV = [&](int n0k) {               // 8 loads of 16B
    ushort_t* dstb = &SMEM[wid * 8192 + 4096];
#pragma unroll
    for (int i = 0; i < 8; ++i) {
      int off = i * 1024 + lane * 16;
      int cv  = off >> 7;
      int c16 = (off >> 4) & 7;
      int sw  = c16 ^ (cv & 7);
      const ushort_t* src = Vb + (size_t)cv * NSP + n0k + sw * 8;
      __builtin_amdgcn_global_load_lds(
          (const __attribute__((address_space(1))) unsigned int*)src,
          (__attribute__((address_space(3))) unsigned int*)&dstb[i * 512], 16, 0, 0);
    }
  };

  // prologue: K0, V0, K1 in flight (FIFO order matters for vmcnt counts)
  stageK(0, kbase);
  stageV(kbase);
  stageK(1, kbase + KB);
  asm volatile("s_waitcnt vmcnt(12)" ::: "memory");  // K0 landed
  __builtin_amdgcn_sched_barrier(0);

#pragma unroll
  for (int t = 0; t < NCH; ++t) {
    const ushort_t* KTc = &SMEM[wid * 8192 + (t & 1) * 2048];
    const ushort_t* VTc = &SMEM[wid * 8192 + 4096];

    // ---- QK^T (swapped): kf read once, reused for both q-groups ----
    bf16x8 kf[4];
#pragma unroll
    for (int kg = 0; kg < 4; ++kg) {
      int key = kg * 16 + l15;
      int sw  = g ^ ((key >> 1) & 3);
      kf[kg] = *(const bf16x8*)&KTc[key * CK + sw * 8];
    }
    f32x4 s[2][4];
    __builtin_amdgcn_s_setprio(1);
#pragma unroll
    for (int qg = 0; qg < 2; ++qg)
#pragma unroll
      for (int kg = 0; kg < 4; ++kg) {
        f32x4 z = {0.f, 0.f, 0.f, 0.f};
        s[qg][kg] = __builtin_amdgcn_mfma_f32_16x16x32_bf16(kf[kg], qf[qg], z, 0, 0, 0);
      }
    __builtin_amdgcn_s_setprio(0);

    // ---- p = exp2(s) + pa pack (independent of V; before the V wait) ----
    float p[2][4][4];
#pragma unroll
    for (int qg = 0; qg < 2; ++qg)
#pragma unroll
      for (int kg = 0; kg < 4; ++kg) {
        float ps = 0.f;
#pragma unroll
        for (int r = 0; r < 4; ++r) {
          p[qg][kg][r] = exp2f(s[qg][kg][r]);
          ps += p[qg][kg][r];
        }
        Ssum[qg] += ps;
      }
    bf16x8 pa[2][2];
#pragma unroll
    for (int ks = 0; ks < 2; ++ks)
#pragma unroll
      for (int qg = 0; qg < 2; ++qg)
#pragma unroll
        for (int j = 0; j < 4; ++j) {
          pa[ks][qg][j]     = (short)f2bf(p[qg][2 * ks][j]);
          pa[ks][qg][4 + j] = (short)f2bf(p[qg][2 * ks + 1][j]);
        }

    // ---- wait V(t) landed (K(t+1)'s 4 loads stay in flight) ----
    if (t < NCH - 1) asm volatile("s_waitcnt vmcnt(4)" ::: "memory");
    else             asm volatile("s_waitcnt vmcnt(0)" ::: "memory");
    __builtin_amdgcn_sched_barrier(0);

    // ---- PV: vf read once per (ks,cg), reused for both q-groups ----
    __builtin_amdgcn_s_setprio(1);
#pragma unroll
    for (int ks = 0; ks < 2; ++ks) {
#pragma unroll
      for (int cg = 0; cg < 4; ++cg) {
        int cv   = cg * 16 + l15;
        int x7   = cv & 7;
        int half = (g & 1) * 4;
        int t0   = (4 * ks + (g >> 1)) ^ x7;
        int t1   = (4 * ks + 2 + (g >> 1)) ^ x7;
        const ushort_t* vrow = &VTc[cv * KB];
        bf16x4 lo = *(const bf16x4*)&vrow[t0 * 8 + half];
        bf16x4 hi = *(const bf16x4*)&vrow[t1 * 8 + half];
        bf16x8 vf;
#pragma unroll
        for (int j = 0; j < 4; ++j) { vf[j] = lo[j]; vf[4 + j] = hi[j]; }
#pragma unroll
        for (int qg = 0; qg < 2; ++qg)
          acc[qg][cg] = __builtin_amdgcn_mfma_f32_16x16x32_bf16(pa[ks][qg], vf, acc[qg][cg], 0, 0, 0);
      }
    }
    __builtin_amdgcn_s_setprio(0);

    // ---- all LDS reads consumed; safe to overwrite V buf and K[t&1] ----
    asm volatile("s_waitcnt lgkmcnt(0)" ::: "memory");
    __builtin_amdgcn_sched_barrier(0);

    if (t + 1 < NCH) stageV(kbase + (t + 1) * KB);          // 8 loads
    if (t + 2 < NCH) stageK(t & 1, kbase + (t + 2) * KB);   // 4 loads

    // ---- wait K(t+1) landed before next iter's QK ----
    if (t + 2 < NCH)      asm volatile("s_waitcnt vmcnt(12)" ::: "memory");
    else if (t + 1 < NCH) asm volatile("s_waitcnt vmcnt(8)" ::: "memory");
    __builtin_amdgcn_sched_barrier(0);
  }

  // ---- per-wave denom finish ----
#pragma unroll
  for (int qg = 0; qg < 2; ++qg) {
    Ssum[qg] += __shfl_xor(Ssum[qg], 16, 64);
    Ssum[qg] += __shfl_xor(Ssum[qg], 32, 64);
  }

  // ---- scatter partials to LDS (reuse tile space) ----
  __syncthreads();
  float* red = (float*)&SMEM[0];              // [8 waves][32 q][68]
  float* SsR = red + NW * 32 * 68;            // [8 waves][32]
#pragma unroll
  for (int qg = 0; qg < 2; ++qg) {
#pragma unroll
    for (int cg = 0; cg < 4; ++cg)
#pragma unroll
      for (int r = 0; r < 4; ++r) {
        int ql = qg * 16 + 4 * g + r;
        red[(wid * 32 + ql) * 68 + cg * 16 + l15] = acc[qg][cg][r];
      }
    if (g == 0) SsR[wid * 32 + qg * 16 + l15] = Ssum[qg];
  }
  __syncthreads();

  // ---- thread-per-slot merge into wave-0 buffer (race-free) ----
  int n  = tid & 31;
  int sl = tid >> 5;                          // 0..15 = v4 slot
  {
    float4_t m4 = *(const float4_t*)&red[n * 68 + sl * 4];
#pragma unroll
    for (int w = 1; w < NW; ++w) {
      float4_t t4 = *(const float4_t*)&red[(w * 32 + n) * 68 + sl * 4];
      m4[0] += t4[0]; m4[1] += t4[1]; m4[2] += t4[2]; m4[3] += t4[3];
    }
    *(float4_t*)&red[n * 68 + sl * 4] = m4;
  }
  if (tid < 32) {
    float ds = 0.f;
#pragma unroll
    for (int w = 0; w < NW; ++w) ds += SsR[w * 32 + tid];
    SsR[tid] = ds;
  }
  __syncthreads();

  // ---- fused proj: 512 threads, 4 outputs each; W from LDS ----
  int og = tid >> 5;                          // 0..15
  float invn = 1.f / SsR[n];

  float pacc[4];
#pragma unroll
  for (int j = 0; j < 4; ++j) pacc[j] = 0.f;
#pragma unroll
  for (int v4 = 0; v4 < 16; ++v4) {
    float4_t c4 = *(const float4_t*)&red[n * 68 + v4 * 4];
#pragma unroll
    for (int j = 0; j < 4; ++j) {
      float4_t w4 = *(const float4_t*)&WL[(og * 4 + j) * CV + v4 * 4];  // broadcast
      pacc[j] += w4[0] * c4[0] + w4[1] * c4[1] + w4[2] * c4[2] + w4[3] * c4[3];
    }
  }

  float gma = gamma[0];
#pragma unroll
  for (int j = 0; j < 4; ++j) {
    int o = og * 4 + j;
    size_t oi = ((size_t)b * COUT + o) * NSP + q0 + n;
    out[oi] = gma * (pacc[j] * invn + Wb[o]) + x[oi];
  }
}

// ---------------------------------------------------------------------------
extern "C" void kernel_launch(void* const* d_in, const int* in_sizes, int n_in,
                              void* d_out, int out_size, void* d_ws, size_t ws_size,
                              hipStream_t stream) {
  const float* x        = (const float*)d_in[0];
  const float* key_w    = (const float*)d_in[1];
  const float* bn_gamma = (const float*)d_in[2];
  const float* bn_beta  = (const float*)d_in[3];
  const float* bn_mean  = (const float*)d_in[4];
  const float* bn_var   = (const float*)d_in[5];
  const float* value_w  = (const float*)d_in[6];
  const float* value_b  = (const float*)d_in[7];
  const float* W_w      = (const float*)d_in[8];
  const float* W_b      = (const float*)d_in[9];
  const float* gamma    = (const float*)d_in[10];
  float* out = (float*)d_out;

  ushort_t* KbT = (ushort_t*)d_ws;                       // [B][N][CK]  bf16
  ushort_t* Vbf = KbT + (size_t)BATCH * NSP * CK;        // [B][CV][N]  bf16

  kv_kernel<<<BATCH * (NSP / 32), 512, 0, stream>>>(
      x, key_w, bn_gamma, bn_beta, bn_mean, bn_var, value_w, value_b, KbT, Vbf);
  attn_proj_kernel<<<BATCH * (NSP / 32), 512, 0, stream>>>(
      KbT, Vbf, W_w, W_b, gamma, x, out);
}